// Round 5
// baseline (601.299 us; speedup 1.0000x reference)
//
#include <hip/hip_runtime.h>
#include <hip/hip_bf16.h>

// DecodeLSTM: B=8192, T=1, H=1024, L=4.  fp32 containers (bf16-rounded values).
// T=1 => layers 1..3: z = h @ (Wx+Wh) + b ; layer 0: z = h0@Wh0 + x*Wx0 + b0.
// R9: TLP via block granularity. 64m x 128z tile, BK=64, 256 thr / 4 waves,
//     48KB LDS double-buffer -> 3 blocks/CU (12 waves/CU), counted VMW(6),
//     NO launch_bounds register cap (spills corrupted R7/R8's vmcnt ledger),
//     lgkmcnt(0) fences before barriers (deterministic LDS ordering).

#define MB_  8192
#define HB_  1024
#define KB_  1024

typedef __attribute__((ext_vector_type(8))) short bf16x8;
typedef __attribute__((ext_vector_type(4))) float f32x4;

#define BAR()   asm volatile("s_barrier" ::: "memory")
#define VMW(n)  asm volatile("s_waitcnt vmcnt(" #n ")" ::: "memory")
#define LGKM0() asm volatile("s_waitcnt lgkmcnt(0)" ::: "memory")

__device__ __forceinline__ void load_lds16(const void* g, void* l) {
  __builtin_amdgcn_global_load_lds(
      (const __attribute__((address_space(1))) unsigned int*)g,
      (__attribute__((address_space(3))) unsigned int*)l, 16, 0, 0);
}

__device__ __forceinline__ float sigmoidf_(float x) { return 1.0f / (1.0f + __expf(-x)); }
__device__ __forceinline__ float tanhf_fast(float x) { return 2.0f / (1.0f + __expf(-2.0f * x)) - 1.0f; }

__device__ __forceinline__ short f2bf(float f) {
  __hip_bfloat16 h = __float2bfloat16(f);
  return *(short*)&h;
}

// ---------------------------------------------------------------------------
// fp32 -> bf16 bulk convert (for h0). 8 elements/thread.
// ---------------------------------------------------------------------------
__global__ __launch_bounds__(256) void cvt_f32_bf16(
    const float* __restrict__ in, __hip_bfloat16* __restrict__ out)
{
  const int i = blockIdx.x * 256 + threadIdx.x;
  const float4 f0 = ((const float4*)in)[i * 2];
  const float4 f1 = ((const float4*)in)[i * 2 + 1];
  bf16x8 v;
  v[0] = f2bf(f0.x); v[1] = f2bf(f0.y); v[2] = f2bf(f0.z); v[3] = f2bf(f0.w);
  v[4] = f2bf(f1.x); v[5] = f2bf(f1.y); v[6] = f2bf(f1.z); v[7] = f2bf(f1.w);
  ((bf16x8*)out)[i] = v;
}

// ---------------------------------------------------------------------------
// Weight prep: WT[L][n][k] bf16  (L=0: Wh0^T ; L>0: (Wx[L-1]+Wh[L-1])^T)
// ---------------------------------------------------------------------------
__global__ __launch_bounds__(256) void prep_weights(
    const float* __restrict__ Wh0,
    const float* __restrict__ Wx,
    const float* __restrict__ Wh,
    __hip_bfloat16* __restrict__ WT)
{
  __shared__ float t[32][33];
  const int L  = blockIdx.z;
  const int n0 = blockIdx.x * 32;
  const int k0 = blockIdx.y * 32;
  const int tx = threadIdx.x & 31;
  const int ty = threadIdx.x >> 5;   // 0..7
  if (L == 0) {
    for (int kk = ty; kk < 32; kk += 8)
      t[kk][tx] = Wh0[(size_t)(k0 + kk) * 4096 + n0 + tx];
  } else {
    const float* wx = Wx + (size_t)(L - 1) * 1024 * 4096;
    const float* wh = Wh + (size_t)(L - 1) * 1024 * 4096;
    for (int kk = ty; kk < 32; kk += 8) {
      size_t idx = (size_t)(k0 + kk) * 4096 + n0 + tx;
      t[kk][tx] = wx[idx] + wh[idx];
    }
  }
  __syncthreads();
  __hip_bfloat16* dst = WT + (size_t)L * 4096 * 1024;
  for (int nn = ty; nn < 32; nn += 8)
    dst[(size_t)(n0 + nn) * 1024 + k0 + tx] = __float2bfloat16(t[tx][nn]);
}

// ---------------------------------------------------------------------------
// Fused LSTM layer. Tile 64m x 128z (32 h-cols x 4 gates), BK=64, 4 waves
// (2m x 2n; per-wave 32m x 64z = acc[2][4]; each lane owns all 4 gates of
// one h-col).  LDS: 2 buffers x (A 8KB + B 16KB) = 48KB -> 3 blocks/CU.
// Swizzle (R6-verified, 128B rows): source colb = ((c&7)^(row&7))<<4;
// read byte = row*128 + ((ks*64 + lq*16) ^ ((l15&7)<<4)).
// Schedule: cin->regs (8 loads); stage(0); iter t<15: stage(t+1) ->
// VMW(6);BAR -> 12 ds_read_b128; LGKM0; BAR -> 16 MFMA.  Peeled t=15 VMW(0).
// vmcnt never 0 mid-loop; NO register cap -> no spills -> ledger intact.
// C/D map: col=lane&15, row=(lane>>4)*4+reg (verified R4/R6).
// ---------------------------------------------------------------------------
template<bool FIRST, bool LAST>
__global__ __launch_bounds__(256) void lstm_layer_kernel(
    const __hip_bfloat16* __restrict__ A,     // [8192][1024] bf16
    const __hip_bfloat16* __restrict__ WT,    // [4096][1024] bf16 (pre-summed)
    const float*          __restrict__ bias,  // [4096] fp32
    const float*                       cin,   // [8192][1024] fp32
    float*                             cout,  // may alias cin (same positions)
    const float*          __restrict__ xvec,  // layer0 x [8192] fp32
    const float*          __restrict__ Wx0,   // layer0 [4096] fp32
    void*                 __restrict__ hout)  // LAST? fp32 : bf16
{
  __shared__ __align__(16) char lds[49152];   // 2 x 24KB buffers

  const int tid  = threadIdx.x;
  const int lane = tid & 63;
  const int wv   = tid >> 6;          // 0..3
  const int wr   = wv & 1;            // m-half (32 rows of 64)
  const int wc   = wv >> 1;           // h-col half (16 of 32)
  const int l15  = lane & 15;
  const int lq   = lane >> 4;         // 0..3
  const int sw   = (l15 & 7) << 4;    // read-side XOR swizzle (R6)

  // bijective XCD map, n-grouped: XCD x owns n-tiles {4x..4x+3} x all 128 m
  // -> B panel per XCD = 1 MB (L2-resident); A served from LLC.
  const int bid = blockIdx.x;
  const int sz  = (bid & 7) * 512 + (bid >> 3);
  const int n0h = (sz >> 7) * 32;     // 32 n-tiles (h-cols)
  const int m0  = (sz & 127) * 64;    // 128 m-tiles

  const int jj = n0h + wc * 16 + l15; // global h-col of this thread

  // cin -> registers (8 scalar loads; drained by the first VMW regardless of
  // where the compiler places them relative to the stage intrinsics).
  float cinv[2][4];
#pragma unroll
  for (int i = 0; i < 2; ++i)
#pragma unroll
    for (int r = 0; r < 4; ++r)
      cinv[i][r] =
          cin[(size_t)(m0 + wr * 32 + i * 16 + (lq << 2) + r) * HB_ + jj];

  // staging source byte-offsets (pre-swizzled, R6 formula; 128B rows)
  unsigned aoff[2], boff[4];
#pragma unroll
  for (int j = 0; j < 2; ++j) {
    const int c    = j * 256 + tid;            // A chunk 0..511 (64 rows)
    const int row  = c >> 3;                   // 0..63
    const int colb = ((c & 7) ^ (row & 7)) << 4;
    aoff[j] = (unsigned)((m0 + row) * 2048 + colb);
  }
#pragma unroll
  for (int j = 0; j < 4; ++j) {
    const int c    = j * 256 + tid;            // B chunk 0..1023 (128 rows)
    const int row  = c >> 3;                   // 0..127
    const int colb = ((c & 7) ^ (row & 7)) << 4;
    const int z    = (row >> 5) * 1024 + n0h + (row & 31);  // gate-major
    boff[j] = (unsigned)(z * 2048 + colb);
  }
  const int ldsu = wv * 1024;          // wave-uniform chunk base (bytes)
  const char* Ab = (const char*)A;
  const char* Wb = (const char*)WT;

  f32x4 acc[2][4] = {};                // [m-frag][gate]

  auto stage = [&](int kt, char* buf) {        // 6 load_lds16 per wave
#pragma unroll
    for (int j = 0; j < 2; ++j)
      load_lds16(Ab + aoff[j] + kt * 128, buf + j * 4096 + ldsu);
#pragma unroll
    for (int j = 0; j < 4; ++j)
      load_lds16(Wb + boff[j] + kt * 128, buf + 8192 + j * 4096 + ldsu);
  };

  auto ktile = [&](const char* buf) {  // 12 ds_read_b128 + 16 MFMA
    bf16x8 Af[2][2], Bf[4][2];
#pragma unroll
    for (int i = 0; i < 2; ++i) {
      const int rl = wr * 32 + i * 16 + l15;   // 0..63
#pragma unroll
      for (int ks = 0; ks < 2; ++ks)
        Af[i][ks] = *(const bf16x8*)(buf + rl * 128 + ((ks * 64 + lq * 16) ^ sw));
    }
#pragma unroll
    for (int g = 0; g < 4; ++g) {
      const int rb = g * 32 + wc * 16 + l15;   // 0..127
#pragma unroll
      for (int ks = 0; ks < 2; ++ks)
        Bf[g][ks] = *(const bf16x8*)(buf + 8192 + rb * 128 +
                                     ((ks * 64 + lq * 16) ^ sw));
    }
    LGKM0();                           // all reads COMPLETE before barrier:
    BAR();                             // next stage may overwrite this buffer
    __builtin_amdgcn_s_setprio(1);
#pragma unroll
    for (int ks = 0; ks < 2; ++ks)
#pragma unroll
      for (int i = 0; i < 2; ++i)
#pragma unroll
        for (int g = 0; g < 4; ++g)
          acc[i][g] = __builtin_amdgcn_mfma_f32_16x16x32_bf16(
              Af[i][ks], Bf[g][ks], acc[i][g], 0, 0, 0);
    __builtin_amdgcn_s_setprio(0);
  };

  // prologue: tile 0 -> buf0
  stage(0, lds);

  for (int t = 0; t < 15; ++t) {
    stage(t + 1, lds + ((t + 1) & 1) * 24576);  // prefetch next tile
    VMW(6); BAR();                    // tile t landed (t+1's 6 in flight)
    ktile(lds + (t & 1) * 24576);
  }
  // peeled final K-tile (t=15, buf1): only here vmcnt drains to 0
  VMW(0); BAR();
  ktile(lds + 24576);

  // ---- epilogue ----
  const float bi  = bias[0 * HB_ + jj];
  const float bf_ = bias[1 * HB_ + jj];
  const float bg  = bias[2 * HB_ + jj];
  const float bo  = bias[3 * HB_ + jj];
  float wxi = 0.f, wxf = 0.f, wxg = 0.f, wxo = 0.f;
  if (FIRST) {
    wxi = Wx0[0 * HB_ + jj];
    wxf = Wx0[1 * HB_ + jj];
    wxg = Wx0[2 * HB_ + jj];
    wxo = Wx0[3 * HB_ + jj];
  }

  // buf0 is dead (last read t=14, completed via LGKM0 before its barrier).
  float* sC = (float*)lds;             // [64][32] fp32 c tile (8 KB)
  float* sH = (float*)(lds + 8192);    // [64][32] fp32 h tile (8 KB)
  const int hl = wc * 16 + l15;        // local h-col 0..31
#pragma unroll
  for (int i = 0; i < 2; ++i) {
#pragma unroll
    for (int r = 0; r < 4; ++r) {
      const int mloc = wr * 32 + i * 16 + (lq << 2) + r;   // local row 0..63
      float zi = acc[i][0][r] + bi;
      float zf = acc[i][1][r] + bf_;
      float zg = acc[i][2][r] + bg;
      float zo = acc[i][3][r] + bo;
      if (FIRST) {
        const float xv = xvec[m0 + mloc];
        zi += xv * wxi; zf += xv * wxf; zg += xv * wxg; zo += xv * wxo;
      }
      const float ig = sigmoidf_(zi);
      const float fg = sigmoidf_(zf);
      const float gg = tanhf_fast(zg);
      const float og = sigmoidf_(zo);
      const float cn = fg * cinv[i][r] + ig * gg;   // cin from registers
      const float hn = og * tanhf_fast(cn);
      sC[mloc * 32 + hl] = cn;
      sH[mloc * 32 + hl] = hn;
    }
  }
  LGKM0(); BAR();                      // c/h writes complete & visible

  // coalesced stores: c (fp32) 64x32 -> 512 float4, 2 passes (256 thr)
#pragma unroll
  for (int p = 0; p < 2; ++p) {
    const int idx = p * 256 + tid;
    const int row = idx >> 3, seg = idx & 7;
    *(float4*)(cout + (size_t)(m0 + row) * HB_ + n0h + seg * 4) =
        *(const float4*)&sC[row * 32 + seg * 4];
  }
  if (LAST) {
#pragma unroll
    for (int p = 0; p < 2; ++p) {
      const int idx = p * 256 + tid;
      const int row = idx >> 3, seg = idx & 7;
      *(float4*)((float*)hout + (size_t)(m0 + row) * HB_ + n0h + seg * 4) =
          *(const float4*)&sH[row * 32 + seg * 4];
    }
  } else {
    const int row = tid >> 2, seg = tid & 3;                // 8 bf16/thread
    const float4 f0 = *(const float4*)&sH[row * 32 + seg * 8];
    const float4 f1 = *(const float4*)&sH[row * 32 + seg * 8 + 4];
    bf16x8 v;
    v[0] = f2bf(f0.x); v[1] = f2bf(f0.y); v[2] = f2bf(f0.z); v[3] = f2bf(f0.w);
    v[4] = f2bf(f1.x); v[5] = f2bf(f1.y); v[6] = f2bf(f1.z); v[7] = f2bf(f1.w);
    *(bf16x8*)((__hip_bfloat16*)hout + (size_t)(m0 + row) * HB_ + n0h + seg * 8) = v;
  }
}

// ---------------------------------------------------------------------------
// Head: x_pred[b] = sum_k h4[b,k]*Wd[k] + bd.  One wave per row. All fp32.
// ---------------------------------------------------------------------------
__global__ __launch_bounds__(256) void head_kernel(
    const float* __restrict__ h,
    const float* __restrict__ Wd,
    const float* __restrict__ bd,
    float* __restrict__ xpred)
{
  const int row  = blockIdx.x * 4 + (threadIdx.x >> 6);
  const int lane = threadIdx.x & 63;
  const float* hr = h + (size_t)row * HB_;
  float s = 0.f;
#pragma unroll
  for (int t = 0; t < 16; ++t) {
    const int k = t * 64 + lane;
    s += hr[k] * Wd[k];
  }
#pragma unroll
  for (int off = 32; off; off >>= 1) s += __shfl_down(s, off, 64);
  if (lane == 0) xpred[row] = s + bd[0];
}

// ---------------------------------------------------------------------------
extern "C" void kernel_launch(void* const* d_in, const int* in_sizes, int n_in,
                              void* d_out, int out_size, void* d_ws, size_t ws_size,
                              hipStream_t stream) {
  (void)in_sizes; (void)n_in; (void)out_size; (void)ws_size;
  const float* x   = (const float*)d_in[0];
  const float* c0  = (const float*)d_in[1];
  const float* h0  = (const float*)d_in[2];
  const float* Wx0 = (const float*)d_in[3];
  const float* Wh0 = (const float*)d_in[4];
  const float* b0  = (const float*)d_in[5];
  const float* Wx  = (const float*)d_in[6];
  const float* Wh  = (const float*)d_in[7];
  const float* b   = (const float*)d_in[8];
  const float* Wd  = (const float*)d_in[9];
  const float* bd  = (const float*)d_in[10];

  float* out_c = (float*)d_out;
  float* out_h = out_c + (size_t)MB_ * HB_;
  float* out_x = out_h + (size_t)MB_ * HB_;

  char* ws = (char*)d_ws;
  __hip_bfloat16* WT = (__hip_bfloat16*)ws;                       // 32 MiB
  __hip_bfloat16* hA = (__hip_bfloat16*)(ws + (size_t)33554432);  // 16 MiB
  __hip_bfloat16* hB = (__hip_bfloat16*)(ws + (size_t)50331648);  // 16 MiB

  const size_t WTL = (size_t)4096 * 1024;

  prep_weights<<<dim3(128, 32, 4), 256, 0, stream>>>(Wh0, Wx, Wh, WT);
  cvt_f32_bf16<<<4096, 256, 0, stream>>>(h0, hA);   // h0 -> bf16 (exact)

  // L0: A=hA(h0 bf16), c: c0 -> out_c ; h1 -> hB
  lstm_layer_kernel<true,  false><<<4096, 256, 0, stream>>>(
      hA, WT, b0, c0, out_c, x, Wx0, hB);
  // L1: A=hB ; c in-place out_c ; h2 -> hA
  lstm_layer_kernel<false, false><<<4096, 256, 0, stream>>>(
      hB, WT + 1 * WTL, b + 0 * 4096, out_c, out_c, nullptr, nullptr, hA);
  // L2: A=hA ; c in-place ; h3 -> hB
  lstm_layer_kernel<false, false><<<4096, 256, 0, stream>>>(
      hA, WT + 2 * WTL, b + 1 * 4096, out_c, out_c, nullptr, nullptr, hB);
  // L3: A=hB ; c in-place (final) ; h4 -> out_h (fp32)
  lstm_layer_kernel<false, true><<<4096, 256, 0, stream>>>(
      hB, WT + 3 * WTL, b + 2 * 4096, out_c, out_c, nullptr, nullptr, out_h);

  head_kernel<<<2048, 256, 0, stream>>>(out_h, Wd, bd, out_x);
}